// Round 9
// baseline (468.456 us; speedup 1.0000x reference)
//
#include <hip/hip_runtime.h>

#define N_ROWS 400000
#define DIM 256
#define NCLS 1000
#define NSQ 6
#define NPOLISH 8

#define NB_S 256      // k_sort blocks
#define NT_S 512
#define NBE  64       // k_eigen blocks (four Gram columns each)
#define NTE  1024
#define NB_P 2048     // k_project blocks
#define NT_P 256
#define TOTW_P (NB_P * (NT_P / 64))   // 8192 waves

typedef float f4 __attribute__((ext_vector_type(4)));

// ---- workspace layout (bytes) ----
#define OFF_BAR     0                 // k_sort barrier counter
#define OFF_BAR2    64                // k_eigen barrier counter
#define OFF_COUNTS  1024              // 1024 u32
#define OFF_MAXBUF  6144              // 16 u32
#define ZERO_BYTES  6208
#define OFF_BASE    6208              // 1024 u32
#define OFF_CURSOR  10304             // 1024 u32
#define OFF_V       14400             // 256 f32
#define OFF_IDX     15424             // 400000 u32
#define OFF_NC      1615424           // [NCLS][DIM] f32
#define OFF_NCT     2639424           // [DIM][NCLS] f32 (transposed)
#define OFF_MA      3663424           // 256 KB
#define OFF_MB      3925568           // 256 KB

// grid barrier: RELAXED spin, one fence on exit. counter zeroed per call.
template <int NBLK>
__device__ __forceinline__ void grid_bar(unsigned* bar, int& phase) {
  __syncthreads();
  if (threadIdx.x == 0) {
    ++phase;
    __threadfence();   // release
    __hip_atomic_fetch_add(bar, 1u, __ATOMIC_RELAXED, __HIP_MEMORY_SCOPE_AGENT);
    const unsigned target = (unsigned)NBLK * (unsigned)phase;
    while (__hip_atomic_load(bar, __ATOMIC_RELAXED, __HIP_MEMORY_SCOPE_AGENT) < target)
      __builtin_amdgcn_s_sleep(8);
    __threadfence();   // acquire
  }
  __syncthreads();
}

// ---------- counting sort of row indices (hist -> scan -> scatter) ----------
__global__ __launch_bounds__(NT_S) void k_sort(const int* __restrict__ labels,
                                               char* __restrict__ ws) {
  unsigned* bar    = (unsigned*)(ws + OFF_BAR);
  unsigned* counts = (unsigned*)(ws + OFF_COUNTS);
  unsigned* base   = (unsigned*)(ws + OFF_BASE);
  unsigned* cursor = (unsigned*)(ws + OFF_CURSOR);
  unsigned* idx    = (unsigned*)(ws + OFF_IDX);

  __shared__ unsigned su[1024];
  const int t = threadIdx.x, b = blockIdx.x;
  int phase = 0;

  for (int i = t; i < NCLS; i += NT_S) su[i] = 0u;
  __syncthreads();
  for (int i = b*NT_S + t; i < N_ROWS; i += NB_S*NT_S)
    atomicAdd(&su[labels[i]], 1u);
  __syncthreads();
  for (int i = t; i < NCLS; i += NT_S) { unsigned v = su[i]; if (v) atomicAdd(&counts[i], v); }
  grid_bar<NB_S>(bar, phase);

  if (b == 0) {
    su[t] = counts[t]; su[t+512] = counts[t+512];
    int offset = 1;
    for (int d = 512; d > 0; d >>= 1) {
      __syncthreads();
      if (t < d) { int ai = offset*(2*t+1)-1, bi = offset*(2*t+2)-1; su[bi] += su[ai]; }
      offset <<= 1;
    }
    __syncthreads();
    if (t == 0) su[1023] = 0u;
    for (int d = 1; d < 1024; d <<= 1) {
      offset >>= 1;
      __syncthreads();
      if (t < d) { int ai = offset*(2*t+1)-1, bi = offset*(2*t+2)-1;
                   unsigned tm = su[ai]; su[ai] = su[bi]; su[bi] += tm; }
    }
    __syncthreads();
    base[t] = su[t]; cursor[t] = su[t];
    base[t+512] = su[t+512]; cursor[t+512] = su[t+512];
  }
  grid_bar<NB_S>(bar, phase);

  for (int i = b*NT_S + t; i < N_ROWS; i += NB_S*NT_S) {
    unsigned p = atomicAdd(&cursor[labels[i]], 1u);
    idx[p] = (unsigned)i;
  }
}

// ---------- per-class gather-mean + EMA -> NC, NCT ----------
__global__ __launch_bounds__(512) void k_reduce(const float* __restrict__ grads,
                                                const unsigned* __restrict__ idx,
                                                const unsigned* __restrict__ base,
                                                const unsigned* __restrict__ counts,
                                                const float* __restrict__ centroids,
                                                float* __restrict__ NC,
                                                float* __restrict__ NCT) {
  const int cls = blockIdx.x;
  const unsigned s0 = base[cls], n = counts[cls];
  const int wave = threadIdx.x >> 6, lane = threadIdx.x & 63;
  const f4* g4 = (const f4*)grads;
  f4 acc = {0.f, 0.f, 0.f, 0.f};
  unsigned u = (unsigned)wave;
  for (; u + 24 < n; u += 32) {               // 4 rows in flight per wave
    unsigned r0 = idx[s0+u],    r1 = idx[s0+u+8];
    unsigned r2 = idx[s0+u+16], r3 = idx[s0+u+24];
    f4 a = __builtin_nontemporal_load(&g4[(size_t)r0*64 + lane]);
    f4 c = __builtin_nontemporal_load(&g4[(size_t)r1*64 + lane]);
    f4 d = __builtin_nontemporal_load(&g4[(size_t)r2*64 + lane]);
    f4 e = __builtin_nontemporal_load(&g4[(size_t)r3*64 + lane]);
    acc += (a + c) + (d + e);
  }
  for (; u < n; u += 8) {
    unsigned r0 = idx[s0+u];
    acc += __builtin_nontemporal_load(&g4[(size_t)r0*64 + lane]);
  }
  __shared__ f4 tmp[8][64];
  tmp[wave][lane] = acc;
  __syncthreads();
  const int d = threadIdx.x;
  if (d < DIM) {
    const float* tf = (const float*)tmp;
    float s = 0.f;
    #pragma unroll
    for (int w2 = 0; w2 < 8; ++w2) s += tf[w2*256 + d];
    float mean = s / fmaxf((float)n, 1.0f);
    float ce = centroids[cls*DIM + d];
    float ncv = (n > 0u) ? (0.9f*ce + 0.1f*mean) : ce;
    NC[cls*DIM + d]  = ncv;
    NCT[d*NCLS + cls] = ncv;                 // transposed copy for eigen staging
  }
}

// ---------- eigenvector chain (coop 64 x 1024, 7 grid barriers) ----------
__global__ __launch_bounds__(NTE) void k_eigen(char* __restrict__ ws) {
  unsigned* bar2   = (unsigned*)(ws + OFF_BAR2);
  unsigned* maxbuf = (unsigned*)(ws + OFF_MAXBUF);
  float*    vfin   = (float*)(ws + OFF_V);
  float*    NC     = (float*)(ws + OFF_NC);
  float*    NCT    = (float*)(ws + OFF_NCT);
  float*    MA     = (float*)(ws + OFF_MA);
  float*    MB     = (float*)(ws + OFF_MB);

  __shared__ float scol[4][1024];    // staged NC columns (P1) / A rows (P2)
  __shared__ f4    sacc[4][16][64];  // per-wave f4 partials, 4 outputs
  __shared__ f4    scs[16][64];      // colsum partials
  __shared__ float colsumv[256];
  __shared__ float red[256];
  __shared__ int   sidx[256];
  __shared__ float sx[256], sy[256];
  __shared__ unsigned smax;

  const int t = threadIdx.x, b = blockIdx.x;
  const int wave = t >> 6, lane = t & 63;
  int phase = 0;
  const f4* NC4 = (const f4*)NC;

  // ---- P1: Gram of centered NC, cols j = b + 64q; colsum folded into sweep ----
  #pragma unroll
  for (int q = 0; q < 4; ++q)
    for (int k = t; k < NCLS; k += NTE) scol[q][k] = NCT[(size_t)(b + 64*q)*NCLS + k];
  if (t == 0) smax = 0u;
  __syncthreads();
  {
    f4 a0 = {0,0,0,0}, a1 = {0,0,0,0}, a2 = {0,0,0,0}, a3 = {0,0,0,0}, cs = {0,0,0,0};
    for (int k = wave; k < NCLS; k += 16) {
      f4 nv = NC4[(size_t)k*64 + lane];            // coalesced row read
      a0 += nv * scol[0][k]; a1 += nv * scol[1][k];
      a2 += nv * scol[2][k]; a3 += nv * scol[3][k];
      cs += nv;
    }
    sacc[0][wave][lane] = a0; sacc[1][wave][lane] = a1;
    sacc[2][wave][lane] = a2; sacc[3][wave][lane] = a3;
    scs[wave][lane] = cs;
  }
  __syncthreads();
  float c0 = 0, c1 = 0, c2 = 0, c3 = 0;
  if (t < 256) {
    const float* p0 = (const float*)sacc[0]; const float* p1 = (const float*)sacc[1];
    const float* p2 = (const float*)sacc[2]; const float* p3 = (const float*)sacc[3];
    const float* pc = (const float*)scs;
    float cc = 0;
    #pragma unroll
    for (int w2 = 0; w2 < 16; ++w2) {
      c0 += p0[w2*256 + t]; c1 += p1[w2*256 + t];
      c2 += p2[w2*256 + t]; c3 += p3[w2*256 + t];
      cc += pc[w2*256 + t];
    }
    colsumv[t] = cc;
  }
  __syncthreads();
  if (t < 256) {
    const float inC = 1.0f / NCLS;
    const float cst = colsumv[t];
    float v0 = c0 - cst*colsumv[b      ]*inC;
    float v1 = c1 - cst*colsumv[b +  64]*inC;
    float v2 = c2 - cst*colsumv[b + 128]*inC;
    float v3 = c3 - cst*colsumv[b + 192]*inC;
    MA[(size_t)(b      )*DIM + t] = v0;
    MA[(size_t)(b +  64)*DIM + t] = v1;
    MA[(size_t)(b + 128)*DIM + t] = v2;
    MA[(size_t)(b + 192)*DIM + t] = v3;
    float am = fmaxf(fmaxf(fabsf(v0), fabsf(v1)), fmaxf(fabsf(v2), fabsf(v3)));
    #pragma unroll
    for (int m = 1; m < 64; m <<= 1) am = fmaxf(am, __shfl_xor(am, m, 64));
    if ((t & 63) == 0) atomicMax(&smax, __float_as_uint(am));
  }
  __syncthreads();
  if (t == 0) atomicMax(maxbuf, smax);
  grid_bar<NBE>(bar2, phase);

  // ---- P2: NSQ normalized squarings ----
  for (int st = 0; st < NSQ; ++st) {
    const float* A = (st & 1) ? MB : MA;
    float*       C = (st & 1) ? MA : MB;
    const f4* A4 = (const f4*)A;
    const float inv = 1.0f / __uint_as_float(maxbuf[st]);
    if (t < 256) {
      scol[0][t] = A[(size_t)(b      )*DIM + t];   // rows == cols (symmetric)
      scol[1][t] = A[(size_t)(b +  64)*DIM + t];
      scol[2][t] = A[(size_t)(b + 128)*DIM + t];
      scol[3][t] = A[(size_t)(b + 192)*DIM + t];
    }
    if (t == 0) smax = 0u;
    __syncthreads();
    {
      f4 a0 = {0,0,0,0}, a1 = {0,0,0,0}, a2 = {0,0,0,0}, a3 = {0,0,0,0};
      for (int k = wave; k < DIM; k += 16) {
        f4 av = A4[(size_t)k*64 + lane];
        a0 += av * scol[0][k]; a1 += av * scol[1][k];
        a2 += av * scol[2][k]; a3 += av * scol[3][k];
      }
      sacc[0][wave][lane] = a0; sacc[1][wave][lane] = a1;
      sacc[2][wave][lane] = a2; sacc[3][wave][lane] = a3;
    }
    __syncthreads();
    float d0 = 0, d1 = 0, d2 = 0, d3 = 0;
    if (t < 256) {
      const float* p0 = (const float*)sacc[0]; const float* p1 = (const float*)sacc[1];
      const float* p2 = (const float*)sacc[2]; const float* p3 = (const float*)sacc[3];
      #pragma unroll
      for (int w2 = 0; w2 < 16; ++w2) {
        d0 += p0[w2*256 + t]; d1 += p1[w2*256 + t];
        d2 += p2[w2*256 + t]; d3 += p3[w2*256 + t];
      }
      const float i2 = inv * inv;
      float v0 = d0*i2, v1 = d1*i2, v2 = d2*i2, v3 = d3*i2;
      C[(size_t)(b      )*DIM + t] = v0;
      C[(size_t)(b +  64)*DIM + t] = v1;
      C[(size_t)(b + 128)*DIM + t] = v2;
      C[(size_t)(b + 192)*DIM + t] = v3;
      float am = fmaxf(fmaxf(fabsf(v0), fabsf(v1)), fmaxf(fabsf(v2), fabsf(v3)));
      #pragma unroll
      for (int m = 1; m < 64; m <<= 1) am = fmaxf(am, __shfl_xor(am, m, 64));
      if ((t & 63) == 0) atomicMax(&smax, __float_as_uint(am));
    }
    __syncthreads();
    if (t == 0) atomicMax(&maxbuf[st+1], smax);
    grid_bar<NBE>(bar2, phase);
  }
  // NSQ=6: final matrix in MA

  // ---- P3: pickcol + NPOLISH power iterations, block 0 only ----
  if (b == 0) {
    const float* M = MA;
    const f4* M4 = (const f4*)MA;
    {
      f4 na = {0,0,0,0};
      for (int k = wave; k < DIM; k += 16) { f4 av = M4[(size_t)k*64 + lane]; na += av*av; }
      sacc[0][wave][lane] = na;
    }
    __syncthreads();
    if (t < 256) {
      const float* p0 = (const float*)sacc[0];
      float s = 0;
      #pragma unroll
      for (int w2 = 0; w2 < 16; ++w2) s += p0[w2*256 + t];
      red[t] = s; sidx[t] = t;
    }
    __syncthreads();
    for (int s2 = 128; s2 > 0; s2 >>= 1) {
      if (t < s2 && red[t+s2] > red[t]) { red[t] = red[t+s2]; sidx[t] = sidx[t+s2]; }
      __syncthreads();
    }
    const int jm = sidx[0];
    const float nrm = sqrtf(fmaxf(red[0], 1e-30f));
    __syncthreads();
    if (t < 256) sx[t] = M[(size_t)jm*DIM + t] / nrm;
    __syncthreads();
    for (int it = 0; it < NPOLISH; ++it) {
      f4 ya = {0,0,0,0};
      for (int k = wave; k < DIM; k += 16) { f4 av = M4[(size_t)k*64 + lane]; ya += av * sx[k]; }
      sacc[0][wave][lane] = ya;
      __syncthreads();
      if (t < 256) {
        const float* p0 = (const float*)sacc[0];
        float s = 0;
        #pragma unroll
        for (int w2 = 0; w2 < 16; ++w2) s += p0[w2*256 + t];
        sy[t] = s; red[t] = s*s;
      }
      __syncthreads();
      for (int s2 = 128; s2 > 0; s2 >>= 1) {
        if (t < s2) red[t] += red[t+s2];
        __syncthreads();
      }
      const float innrm = rsqrtf(fmaxf(red[0], 1e-30f));
      __syncthreads();
      if (t < 256) sx[t] = sy[t] * innrm;
      __syncthreads();
    }
    if (t < 256) vfin[t] = sx[t];
  }
}

// ---------- projection out = g - (g.v) v (nontemporal streaming) ----------
__global__ __launch_bounds__(NT_P) void k_project(const f4* __restrict__ g4,
                                                  const float* __restrict__ v,
                                                  f4* __restrict__ out) {
  const int lane = threadIdx.x & 63;
  const f4 v4 = ((const f4*)v)[lane];
  const int w = blockIdx.x * (NT_P/64) + (threadIdx.x >> 6);
  int r = w;
  for (; r + TOTW_P < N_ROWS; r += 2*TOTW_P) {
    f4 a = __builtin_nontemporal_load(&g4[(size_t)r*64 + lane]);
    f4 c = __builtin_nontemporal_load(&g4[(size_t)(r+TOTW_P)*64 + lane]);
    float da = a.x*v4.x + a.y*v4.y + a.z*v4.z + a.w*v4.w;
    float db = c.x*v4.x + c.y*v4.y + c.z*v4.z + c.w*v4.w;
    #pragma unroll
    for (int m = 1; m < 64; m <<= 1) { da += __shfl_xor(da, m, 64); db += __shfl_xor(db, m, 64); }
    f4 o0 = a - da * v4;
    f4 o1 = c - db * v4;
    __builtin_nontemporal_store(o0, &out[(size_t)r*64 + lane]);
    __builtin_nontemporal_store(o1, &out[(size_t)(r+TOTW_P)*64 + lane]);
  }
  for (; r < N_ROWS; r += TOTW_P) {
    f4 a = __builtin_nontemporal_load(&g4[(size_t)r*64 + lane]);
    float da = a.x*v4.x + a.y*v4.y + a.z*v4.z + a.w*v4.w;
    #pragma unroll
    for (int m = 1; m < 64; m <<= 1) da += __shfl_xor(da, m, 64);
    f4 o = a - da * v4;
    __builtin_nontemporal_store(o, &out[(size_t)r*64 + lane]);
  }
}

extern "C" void kernel_launch(void* const* d_in, const int* in_sizes, int n_in,
                              void* d_out, int out_size, void* d_ws, size_t ws_size,
                              hipStream_t stream) {
  const float* grads     = (const float*)d_in[0];
  const int*   labels    = (const int*)d_in[1];
  const float* centroids = (const float*)d_in[2];
  float* out = (float*)d_out;
  char* ws = (char*)d_ws;

  unsigned* idx    = (unsigned*)(ws + OFF_IDX);
  unsigned* counts = (unsigned*)(ws + OFF_COUNTS);
  unsigned* base   = (unsigned*)(ws + OFF_BASE);
  float*    vfin   = (float*)(ws + OFF_V);
  float*    NC     = (float*)(ws + OFF_NC);
  float*    NCT    = (float*)(ws + OFF_NCT);

  (void)hipMemsetAsync(ws, 0, ZERO_BYTES, stream);

  k_sort<<<NB_S, NT_S, 0, stream>>>(labels, ws);
  k_reduce<<<NCLS, 512, 0, stream>>>(grads, idx, base, counts, centroids, NC, NCT);
  k_eigen<<<NBE, NTE, 0, stream>>>(ws);
  k_project<<<NB_P, NT_P, 0, stream>>>((const f4*)grads, vfin, (f4*)out);
}

// Round 10
// 440.637 us; speedup vs baseline: 1.0631x; 1.0631x over previous
//
#include <hip/hip_runtime.h>

#define N_ROWS 400000
#define DIM 256
#define NCLS 1000
#define NSQ 6
#define NPOLISH 8

#define NB_S 256      // k_sort blocks
#define NT_S 512
#define NBE  64       // k_eigen blocks (four Gram columns each)
#define NTE  1024
#define NB_P 2048     // k_project blocks
#define NT_P 256
#define TOTW_P (NB_P * (NT_P / 64))   // 8192 waves

typedef float f4 __attribute__((ext_vector_type(4)));   // native vec for nontemporal builtins

// ---- workspace layout (bytes) ----
#define OFF_BAR     0                 // k_sort barrier counter
#define OFF_BAR2    64                // k_eigen barrier counter
#define OFF_COUNTS  1024              // 1024 u32
#define OFF_COLSUM  5120              // 256 f32
#define OFF_MAXBUF  6144              // 16 u32
#define ZERO_BYTES  6208
#define OFF_BASE    6208              // 1024 u32
#define OFF_CURSOR  10304             // 1024 u32
#define OFF_V       14400             // 256 f32
#define OFF_IDX     15424             // 400000 u32
#define OFF_NC      1615424           // [NCLS][DIM] f32
#define OFF_NCT     2639424           // [DIM][NCLS] f32 (transposed)
#define OFF_MA      3663424           // 256 KB
#define OFF_MB      3925568           // 256 KB

// grid barrier: RELAXED spin, one fence on exit. counter zeroed per call.
template <int NBLK>
__device__ __forceinline__ void grid_bar(unsigned* bar, int& phase) {
  __syncthreads();
  if (threadIdx.x == 0) {
    ++phase;
    __threadfence();   // release
    __hip_atomic_fetch_add(bar, 1u, __ATOMIC_RELAXED, __HIP_MEMORY_SCOPE_AGENT);
    const unsigned target = (unsigned)NBLK * (unsigned)phase;
    while (__hip_atomic_load(bar, __ATOMIC_RELAXED, __HIP_MEMORY_SCOPE_AGENT) < target)
      __builtin_amdgcn_s_sleep(8);
    __threadfence();   // acquire
  }
  __syncthreads();
}

// ---------- counting sort of row indices (hist -> scan -> scatter) ----------
__global__ __launch_bounds__(NT_S) void k_sort(const int* __restrict__ labels,
                                               char* __restrict__ ws) {
  unsigned* bar    = (unsigned*)(ws + OFF_BAR);
  unsigned* counts = (unsigned*)(ws + OFF_COUNTS);
  unsigned* base   = (unsigned*)(ws + OFF_BASE);
  unsigned* cursor = (unsigned*)(ws + OFF_CURSOR);
  unsigned* idx    = (unsigned*)(ws + OFF_IDX);

  __shared__ unsigned su[1024];
  const int t = threadIdx.x, b = blockIdx.x;
  int phase = 0;

  for (int i = t; i < NCLS; i += NT_S) su[i] = 0u;
  __syncthreads();
  for (int i = b*NT_S + t; i < N_ROWS; i += NB_S*NT_S)
    atomicAdd(&su[labels[i]], 1u);
  __syncthreads();
  for (int i = t; i < NCLS; i += NT_S) { unsigned v = su[i]; if (v) atomicAdd(&counts[i], v); }
  grid_bar<NB_S>(bar, phase);

  if (b == 0) {
    su[t] = counts[t]; su[t+512] = counts[t+512];
    int offset = 1;
    for (int d = 512; d > 0; d >>= 1) {
      __syncthreads();
      if (t < d) { int ai = offset*(2*t+1)-1, bi = offset*(2*t+2)-1; su[bi] += su[ai]; }
      offset <<= 1;
    }
    __syncthreads();
    if (t == 0) su[1023] = 0u;
    for (int d = 1; d < 1024; d <<= 1) {
      offset >>= 1;
      __syncthreads();
      if (t < d) { int ai = offset*(2*t+1)-1, bi = offset*(2*t+2)-1;
                   unsigned tm = su[ai]; su[ai] = su[bi]; su[bi] += tm; }
    }
    __syncthreads();
    base[t] = su[t]; cursor[t] = su[t];
    base[t+512] = su[t+512]; cursor[t+512] = su[t+512];
  }
  grid_bar<NB_S>(bar, phase);

  for (int i = b*NT_S + t; i < N_ROWS; i += NB_S*NT_S) {
    unsigned p = atomicAdd(&cursor[labels[i]], 1u);
    idx[p] = (unsigned)i;
  }
}

// ---------- per-class gather-mean + EMA -> NC, NCT, colsum ----------
__global__ __launch_bounds__(512) void k_reduce(const float* __restrict__ grads,
                                                const unsigned* __restrict__ idx,
                                                const unsigned* __restrict__ base,
                                                const unsigned* __restrict__ counts,
                                                const float* __restrict__ centroids,
                                                float* __restrict__ NC,
                                                float* __restrict__ NCT,
                                                float* __restrict__ colsum) {
  const int cls = blockIdx.x;
  const unsigned s0 = base[cls], n = counts[cls];
  const int wave = threadIdx.x >> 6, lane = threadIdx.x & 63;
  const f4* g4 = (const f4*)grads;
  f4 acc = {0.f, 0.f, 0.f, 0.f};
  unsigned u = (unsigned)wave;
  for (; u + 56 < n; u += 64) {               // 8 rows in flight per wave
    unsigned r0 = idx[s0+u],    r1 = idx[s0+u+8];
    unsigned r2 = idx[s0+u+16], r3 = idx[s0+u+24];
    unsigned r4 = idx[s0+u+32], r5 = idx[s0+u+40];
    unsigned r6 = idx[s0+u+48], r7 = idx[s0+u+56];
    f4 a0 = g4[(size_t)r0*64 + lane];
    f4 a1 = g4[(size_t)r1*64 + lane];
    f4 a2 = g4[(size_t)r2*64 + lane];
    f4 a3 = g4[(size_t)r3*64 + lane];
    f4 a4 = g4[(size_t)r4*64 + lane];
    f4 a5 = g4[(size_t)r5*64 + lane];
    f4 a6 = g4[(size_t)r6*64 + lane];
    f4 a7 = g4[(size_t)r7*64 + lane];
    acc += ((a0 + a1) + (a2 + a3)) + ((a4 + a5) + (a6 + a7));
  }
  for (; u < n; u += 8) {
    unsigned r0 = idx[s0+u];
    acc += g4[(size_t)r0*64 + lane];
  }
  __shared__ f4 tmp[8][64];
  tmp[wave][lane] = acc;
  __syncthreads();
  const int d = threadIdx.x;
  if (d < DIM) {
    const float* tf = (const float*)tmp;
    float s = 0.f;
    #pragma unroll
    for (int w2 = 0; w2 < 8; ++w2) s += tf[w2*256 + d];
    float mean = s / fmaxf((float)n, 1.0f);
    float ce = centroids[cls*DIM + d];
    float ncv = (n > 0u) ? (0.9f*ce + 0.1f*mean) : ce;
    NC[cls*DIM + d]  = ncv;
    NCT[d*NCLS + cls] = ncv;                 // transposed copy for eigen
    atomicAdd(&colsum[d], ncv);
  }
}

// ---------- eigenvector chain (coop 64 x 1024, 7 grid barriers) ----------
__global__ __launch_bounds__(NTE) void k_eigen(char* __restrict__ ws) {
  unsigned* bar2   = (unsigned*)(ws + OFF_BAR2);
  float*    colsum = (float*)(ws + OFF_COLSUM);
  unsigned* maxbuf = (unsigned*)(ws + OFF_MAXBUF);
  float*    vfin   = (float*)(ws + OFF_V);
  float*    NC     = (float*)(ws + OFF_NC);
  float*    NCT    = (float*)(ws + OFF_NCT);
  float*    MA     = (float*)(ws + OFF_MA);
  float*    MB     = (float*)(ws + OFF_MB);

  __shared__ float scol[4][NCLS];    // staged columns/rows
  __shared__ float sf[4][NTE];       // k-split partials
  __shared__ float sx[DIM], sy[DIM];
  __shared__ int   sidx[256];
  __shared__ unsigned smax;

  const int t = threadIdx.x, b = blockIdx.x;
  const int i = t & 255, h = t >> 8;           // output row, k-chunk (0..3)
  int phase = 0;

  // P1: Gram of centered NC, columns j = b + 64q (coalesced via NCT)
  {
    #pragma unroll
    for (int q = 0; q < 4; ++q)
      if (t < NCLS) scol[q][t] = NCT[(size_t)(b + 64*q)*NCLS + t];
    if (t == 0) smax = 0u;
    __syncthreads();
    float a0 = 0.f, a1 = 0.f, a2 = 0.f, a3 = 0.f;
    const int k0 = h * 250;
    #pragma unroll 5
    for (int k = k0; k < k0 + 250; ++k) {
      float nv = NC[k*DIM + i];
      a0 += nv * scol[0][k]; a1 += nv * scol[1][k];
      a2 += nv * scol[2][k]; a3 += nv * scol[3][k];
    }
    sf[0][t] = a0; sf[1][t] = a1; sf[2][t] = a2; sf[3][t] = a3;
    __syncthreads();
    if (h == 0) {
      float am = 0.f;
      #pragma unroll
      for (int q = 0; q < 4; ++q) {
        const int j = b + 64*q;
        float v = sf[q][i]+sf[q][i+256]+sf[q][i+512]+sf[q][i+768]
                - colsum[i]*colsum[j]*(1.0f/NCLS);
        MA[j*DIM + i] = v;
        am = fmaxf(am, fabsf(v));
      }
      #pragma unroll
      for (int m = 1; m < 64; m <<= 1) am = fmaxf(am, __shfl_xor(am, m, 64));
      if ((t & 63) == 0) atomicMax(&smax, __float_as_uint(am));
    }
    __syncthreads();
    if (t == 0) atomicMax(maxbuf, smax);
  }
  grid_bar<NBE>(bar2, phase);

  // P2: NSQ normalized squarings, columns j = b + 64q each step
  for (int st = 0; st < NSQ; ++st) {
    const float* A = (st & 1) ? MB : MA;
    float*       C = (st & 1) ? MA : MB;
    const float inv = 1.0f / __uint_as_float(maxbuf[st]);
    #pragma unroll
    for (int q = 0; q < 4; ++q)
      if (t < DIM) scol[q][t] = A[(b + 64*q)*DIM + t];   // rows==cols (sym)
    if (t == 0) smax = 0u;
    __syncthreads();
    float a0 = 0.f, a1 = 0.f, a2 = 0.f, a3 = 0.f;
    const int k0 = h * 64;
    #pragma unroll 8
    for (int k = k0; k < k0 + 64; ++k) {
      float av = A[k*DIM + i];
      a0 += av * scol[0][k]; a1 += av * scol[1][k];
      a2 += av * scol[2][k]; a3 += av * scol[3][k];
    }
    sf[0][t] = a0; sf[1][t] = a1; sf[2][t] = a2; sf[3][t] = a3;
    __syncthreads();
    if (h == 0) {
      float am = 0.f;
      #pragma unroll
      for (int q = 0; q < 4; ++q) {
        const int j = b + 64*q;
        float v = (sf[q][i]+sf[q][i+256]+sf[q][i+512]+sf[q][i+768]) * inv * inv;
        C[j*DIM + i] = v;
        am = fmaxf(am, fabsf(v));
      }
      #pragma unroll
      for (int m = 1; m < 64; m <<= 1) am = fmaxf(am, __shfl_xor(am, m, 64));
      if ((t & 63) == 0) atomicMax(&smax, __float_as_uint(am));
    }
    __syncthreads();
    if (t == 0) atomicMax(&maxbuf[st+1], smax);
    grid_bar<NBE>(bar2, phase);
  }
  // NSQ even -> final matrix in MA

  // P3: pickcol + NPOLISH power-polish iterations, block 0 only
  if (b == 0) {
    const int k0 = h * 64;
    float ns = 0.f;
    for (int k = k0; k < k0 + 64; ++k) { float x = MA[k*DIM + i]; ns += x*x; }
    sf[0][t] = ns;
    __syncthreads();
    if (h == 0) {
      scol[0][i] = sf[0][i]+sf[0][i+256]+sf[0][i+512]+sf[0][i+768];
      sidx[i] = i;
    }
    __syncthreads();
    for (int s = 128; s > 0; s >>= 1) {
      if (t < s && scol[0][t+s] > scol[0][t]) { scol[0][t] = scol[0][t+s]; sidx[t] = sidx[t+s]; }
      __syncthreads();
    }
    const int jm = sidx[0];
    const float nrm = sqrtf(fmaxf(scol[0][0], 1e-30f));
    __syncthreads();
    if (t < DIM) sx[t] = MA[(size_t)jm*DIM + t] / nrm;
    __syncthreads();
    for (int it = 0; it < NPOLISH; ++it) {
      float a2 = 0.f;
      #pragma unroll 8
      for (int k = k0; k < k0 + 64; ++k) a2 += MA[k*DIM + i] * sx[k];
      sf[0][t] = a2;
      __syncthreads();
      if (h == 0) {
        float yv = sf[0][i]+sf[0][i+256]+sf[0][i+512]+sf[0][i+768];
        sy[i] = yv;
        float q = yv*yv;
        #pragma unroll
        for (int m = 1; m < 64; m <<= 1) q += __shfl_xor(q, m, 64);
        if ((i & 63) == 0) scol[0][i >> 6] = q;
      }
      __syncthreads();
      const float innrm = rsqrtf(fmaxf(scol[0][0]+scol[0][1]+scol[0][2]+scol[0][3], 1e-30f));
      if (t < DIM) sx[t] = sy[t] * innrm;
      __syncthreads();
    }
    if (t < DIM) vfin[t] = sx[t];
  }
}

// ---------- projection out = g - (g.v) v (nontemporal streaming) ----------
__global__ __launch_bounds__(NT_P) void k_project(const f4* __restrict__ g4,
                                                  const float* __restrict__ v,
                                                  f4* __restrict__ out) {
  const int lane = threadIdx.x & 63;
  const f4 v4 = ((const f4*)v)[lane];
  const int w = blockIdx.x * (NT_P/64) + (threadIdx.x >> 6);
  int r = w;
  for (; r + TOTW_P < N_ROWS; r += 2*TOTW_P) {
    f4 a = __builtin_nontemporal_load(&g4[(size_t)r*64 + lane]);
    f4 c = __builtin_nontemporal_load(&g4[(size_t)(r+TOTW_P)*64 + lane]);
    float da = a.x*v4.x + a.y*v4.y + a.z*v4.z + a.w*v4.w;
    float db = c.x*v4.x + c.y*v4.y + c.z*v4.z + c.w*v4.w;
    #pragma unroll
    for (int m = 1; m < 64; m <<= 1) { da += __shfl_xor(da, m, 64); db += __shfl_xor(db, m, 64); }
    f4 o0 = a - da * v4;
    f4 o1 = c - db * v4;
    __builtin_nontemporal_store(o0, &out[(size_t)r*64 + lane]);
    __builtin_nontemporal_store(o1, &out[(size_t)(r+TOTW_P)*64 + lane]);
  }
  for (; r < N_ROWS; r += TOTW_P) {
    f4 a = __builtin_nontemporal_load(&g4[(size_t)r*64 + lane]);
    float da = a.x*v4.x + a.y*v4.y + a.z*v4.z + a.w*v4.w;
    #pragma unroll
    for (int m = 1; m < 64; m <<= 1) da += __shfl_xor(da, m, 64);
    f4 o = a - da * v4;
    __builtin_nontemporal_store(o, &out[(size_t)r*64 + lane]);
  }
}

extern "C" void kernel_launch(void* const* d_in, const int* in_sizes, int n_in,
                              void* d_out, int out_size, void* d_ws, size_t ws_size,
                              hipStream_t stream) {
  const float* grads     = (const float*)d_in[0];
  const int*   labels    = (const int*)d_in[1];
  const float* centroids = (const float*)d_in[2];
  float* out = (float*)d_out;
  char* ws = (char*)d_ws;

  unsigned* idx    = (unsigned*)(ws + OFF_IDX);
  unsigned* counts = (unsigned*)(ws + OFF_COUNTS);
  unsigned* base   = (unsigned*)(ws + OFF_BASE);
  float*    colsum = (float*)(ws + OFF_COLSUM);
  float*    vfin   = (float*)(ws + OFF_V);
  float*    NC     = (float*)(ws + OFF_NC);
  float*    NCT    = (float*)(ws + OFF_NCT);

  (void)hipMemsetAsync(ws, 0, ZERO_BYTES, stream);

  k_sort<<<NB_S, NT_S, 0, stream>>>(labels, ws);
  k_reduce<<<NCLS, 512, 0, stream>>>(grads, idx, base, counts, centroids, NC, NCT, colsum);
  k_eigen<<<NBE, NTE, 0, stream>>>(ws);
  k_project<<<NB_P, NT_P, 0, stream>>>((const f4*)grads, vfin, (f4*)out);
}